// Round 12
// baseline (175.281 us; speedup 1.0000x reference)
//
#include <hip/hip_runtime.h>
#include <hip/hip_fp16.h>

#define LOG2E 1.44269504088896340736f
#define DM 1536
#define LL  2048
#define NN  16
#define NCH 256    // chunks per row (across 4 waves)
#define CL  8      // steps per chunk = LL / NCH

__device__ __forceinline__ float fexp2(float v){ return __builtin_amdgcn_exp2f(v); }
__device__ __forceinline__ float frcp(float v){ return __builtin_amdgcn_rcpf(v); }

__device__ __forceinline__ float packdx(float d, float x){
    unsigned u = (unsigned)__half_as_ushort(__float2half_rn(d))
               | ((unsigned)__half_as_ushort(__float2half_rn(x)) << 16);
    return __uint_as_float(u);
}
__device__ __forceinline__ void unpackdx(float f, float& d, float& x){
    const unsigned u = __float_as_uint(f);
    d = __half2float(__ushort_as_half((unsigned short)(u & 0xffffu)));
    x = __half2float(__ushort_as_half((unsigned short)(u >> 16)));
}
// float4 = 8 packed halfs -> 8 floats
__device__ __forceinline__ void unpack8(const float4 f, float* o){
    const unsigned u0=__float_as_uint(f.x), u1=__float_as_uint(f.y),
                   u2=__float_as_uint(f.z), u3=__float_as_uint(f.w);
    o[0]=__half2float(__ushort_as_half((unsigned short)(u0&0xffffu)));
    o[1]=__half2float(__ushort_as_half((unsigned short)(u0>>16)));
    o[2]=__half2float(__ushort_as_half((unsigned short)(u1&0xffffu)));
    o[3]=__half2float(__ushort_as_half((unsigned short)(u1>>16)));
    o[4]=__half2float(__ushort_as_half((unsigned short)(u2&0xffffu)));
    o[5]=__half2float(__ushort_as_half((unsigned short)(u2>>16)));
    o[6]=__half2float(__ushort_as_half((unsigned short)(u3&0xffffu)));
    o[7]=__half2float(__ushort_as_half((unsigned short)(u3>>16)));
}

// B,C fp32 [b][n][t] -> fp16 records: BC[((b*8 + (t&7))*256 + (t>>3))*32 + n]
// (B at +n, C at +16+n). Per (step r, chunk c) one contiguous 64 B record.
__global__ __launch_bounds__(256) void transpose_bc(
        const float* __restrict__ Bm, const float* __restrict__ Cm,
        __half* __restrict__ BC){
    const int q  = blockIdx.x*256 + threadIdx.x;   // 16384 float4 quads
    const int t0 = (q & 511) << 2;
    const int n  = (q >> 9) & 15;
    const int b  = q >> 13;
    const long i = (long)(b*NN + n)*LL + t0;
    const float4 bv = *(const float4*)(Bm + i);
    const float4 cv = *(const float4*)(Cm + i);
    const float bb[4]={bv.x,bv.y,bv.z,bv.w}, cc[4]={cv.x,cv.y,cv.z,cv.w};
#pragma unroll
    for (int j=0;j<4;++j){
        const int t = t0 + j;
        const long o = ((long)((b*CL + (t&7))*NCH + (t>>3)))*32 + n;
        BC[o]      = __float2half_rn(bb[j]);
        BC[o + 16] = __float2half_rn(cc[j]);
    }
}

// Block = 4 waves = ONE row-pair. 256 chunks x 8 steps; wave w owns chunks
// [w*64, w*64+64). Thread carries 16 states x 2 rows. Two-level scan:
// KS within wave; wave totals -> 1 KB LDS -> one barrier -> fold preceding
// waves' totals. Identical to r10 EXCEPT the launch bound: plain (256), no
// min-waves squeeze. r10's (256,5) forced a 102-VGPR cap against ~150 live
// floats -> allocator spilled everything (VGPR 48, WRITE 118 MB, 125 us).
// Natural allocation (~84-110 VGPR, cf. r9's 84) -> 5 waves/SIMD -> 20
// waves/CU vs r9's 12, same instruction stream as r9's 64 us kernel.
__global__ __launch_bounds__(256) void ssm_scan(
    const float* __restrict__ x, const float* __restrict__ delta,
    const float* __restrict__ A, const float* __restrict__ Dv,
    const float* __restrict__ z, const __half* __restrict__ BC,
    float* __restrict__ out)
{
    __shared__ float2 sdx[CL*NCH];        // 16 KB
    __shared__ float  wtot[4][2][2][NN];  // [wave][P=0/G=1][row][n]

    const int lane = threadIdx.x & 63;
    const int w    = threadIdx.x >> 6;
    const int row0 = blockIdx.x*2;           // b*DM + d ; row1 = row0+1
    const int b    = (row0 >= DM) ? 1 : 0;
    const int d0   = row0 - b*DM;
    const int cmy  = w*64 + lane;            // my chunk (0..255)

    const long base0 = (long)row0*LL;
    const long base1 = base0 + LL;
    const float* gd0 = delta + base0; const float* gx0 = x + base0;
    const float* gd1 = delta + base1; const float* gx1 = x + base1;

    // ---- stage packed (d,x), both rows; wave w covers t in [w*512, +512)
    // -> chunks c = t>>3 in [64w, 64w+64) = exactly this wave's chunks.
    for (int k=0;k<512;k+=256){
        const int t0 = w*512 + k + lane*4;
        const float4 dv0 = *(const float4*)(gd0 + t0);
        const float4 xv0 = *(const float4*)(gx0 + t0);
        const float4 dv1 = *(const float4*)(gd1 + t0);
        const float4 xv1 = *(const float4*)(gx1 + t0);
        const float dd0[4]={dv0.x,dv0.y,dv0.z,dv0.w}, xx0[4]={xv0.x,xv0.y,xv0.z,xv0.w};
        const float dd1[4]={dv1.x,dv1.y,dv1.z,dv1.w}, xx1[4]={xv1.x,xv1.y,xv1.z,xv1.w};
#pragma unroll
        for (int j=0;j<4;++j){
            const int t = t0 + j, r = t & 7, c = t >> 3;
            float2 wd; wd.x = packdx(dd0[j], xx0[j]); wd.y = packdx(dd1[j], xx1[j]);
            sdx[r*NCH + (c^r)] = wd;
        }
    }

    float A20[NN], A21[NN];
#pragma unroll
    for (int n=0;n<NN;++n){
        A20[n] = A[d0*NN+n]     * LOG2E;
        A21[n] = A[(d0+1)*NN+n] * LOG2E;
    }

    // record for (b, r, chunk cmy): BC + b*65536 + r*8192 + cmy*32 (halfs)
    const __half* bc = BC + (long)b*65536 + cmy*32;

    // ---- phase 1: local chunk scan h0=0 -> G (both rows); dsum -> P
    float G0[NN], G1[NN];
#pragma unroll
    for (int n=0;n<NN;++n){ G0[n]=0.f; G1[n]=0.f; }
    float ds0=0.f, ds1=0.f;
#pragma unroll 2
    for (int r=0;r<CL;++r){
        const float2 wd = sdx[r*NCH + (cmy^r)];
        const float4* rec = (const float4*)(bc + (long)r*8192);
        float bb[16];
        unpack8(rec[0], bb); unpack8(rec[1], bb+8);
        float d_0,x_0,d_1,x_1;
        unpackdx(wd.x, d_0, x_0); unpackdx(wd.y, d_1, x_1);
        ds0 += d_0; ds1 += d_1;
        const float dx0 = d_0*x_0, dx1 = d_1*x_1;
#pragma unroll
        for (int n=0;n<NN;++n){
            const float e0 = fexp2(d_0*A20[n]);
            G0[n] = __builtin_fmaf(e0, G0[n], bb[n]*dx0);
            const float e1 = fexp2(d_1*A21[n]);
            G1[n] = __builtin_fmaf(e1, G1[n], bb[n]*dx1);
        }
    }

    // ---- phase 2: two-level scan (KS within wave + LDS compose across 4)
    float h0[NN], h1[NN];
    {
        float P0[NN], P1[NN];
#pragma unroll
        for (int n=0;n<NN;++n){ P0[n]=fexp2(ds0*A20[n]); P1[n]=fexp2(ds1*A21[n]); }
#pragma unroll
        for (int s=1;s<64;s<<=1){
#pragma unroll
            for (int n=0;n<NN;++n){
                const float pl0=__shfl_up(P0[n],s), gl0=__shfl_up(G0[n],s);
                const float pl1=__shfl_up(P1[n],s), gl1=__shfl_up(G1[n],s);
                if (lane >= s){
                    G0[n]=__builtin_fmaf(P0[n],gl0,G0[n]); P0[n]*=pl0;
                    G1[n]=__builtin_fmaf(P1[n],gl1,G1[n]); P1[n]*=pl1;
                }
            }
        }
        if (lane==63){
#pragma unroll
            for (int n=0;n<NN;++n){
                wtot[w][0][0][n]=P0[n]; wtot[w][1][0][n]=G0[n];
                wtot[w][0][1][n]=P1[n]; wtot[w][1][1][n]=G1[n];
            }
        }
        __syncthreads();
#pragma unroll
        for (int n=0;n<NN;++n){
            float bs0 = 0.f, bs1 = 0.f;
            for (int ww=0; ww<w; ++ww){     // wave-uniform loop (w<=3)
                bs0 = __builtin_fmaf(wtot[ww][0][0][n], bs0, wtot[ww][1][0][n]);
                bs1 = __builtin_fmaf(wtot[ww][0][1][n], bs1, wtot[ww][1][1][n]);
            }
            const float pe0=__shfl_up(P0[n],1), ge0=__shfl_up(G0[n],1);
            const float pe1=__shfl_up(P1[n],1), ge1=__shfl_up(G1[n],1);
            const float Px0 = (lane==0)?1.f:pe0, Gx0 = (lane==0)?0.f:ge0;
            const float Px1 = (lane==0)?1.f:pe1, Gx1 = (lane==0)?0.f:ge1;
            h0[n] = __builtin_fmaf(Px0, bs0, Gx0);
            h1[n] = __builtin_fmaf(Px1, bs1, Gx1);
        }
    }

    // ---- phase 3: re-scan with true h_start; stash fp32 {y0+x0*D0, y1+x1*D1}
    const float Dd0 = Dv[d0], Dd1 = Dv[d0+1];
#pragma unroll 2
    for (int r=0;r<CL;++r){
        const int slot = r*NCH + (cmy^r);
        const float2 wd = sdx[slot];
        const float4* rec = (const float4*)(bc + (long)r*8192);
        float bb[16], cc[16];
        unpack8(rec[0], bb); unpack8(rec[1], bb+8);
        unpack8(rec[2], cc); unpack8(rec[3], cc+8);
        float d_0,x_0,d_1,x_1;
        unpackdx(wd.x, d_0, x_0); unpackdx(wd.y, d_1, x_1);
        const float dx0 = d_0*x_0, dx1 = d_1*x_1;
        float ya0=0.f, yb0=0.f, ya1=0.f, yb1=0.f;
#pragma unroll
        for (int n=0;n<NN;n+=2){
            const float e0a = fexp2(d_0*A20[n]);
            h0[n]  =__builtin_fmaf(e0a,h0[n],  bb[n]*dx0);   ya0=__builtin_fmaf(h0[n],  cc[n],  ya0);
            const float e0b = fexp2(d_0*A20[n+1]);
            h0[n+1]=__builtin_fmaf(e0b,h0[n+1],bb[n+1]*dx0); yb0=__builtin_fmaf(h0[n+1],cc[n+1],yb0);
            const float e1a = fexp2(d_1*A21[n]);
            h1[n]  =__builtin_fmaf(e1a,h1[n],  bb[n]*dx1);   ya1=__builtin_fmaf(h1[n],  cc[n],  ya1);
            const float e1b = fexp2(d_1*A21[n+1]);
            h1[n+1]=__builtin_fmaf(e1b,h1[n+1],bb[n+1]*dx1); yb1=__builtin_fmaf(h1[n+1],cc[n+1],yb1);
        }
        float2 yo;
        yo.x = __builtin_fmaf(x_0, Dd0, ya0+yb0);
        yo.y = __builtin_fmaf(x_1, Dd1, ya1+yb1);
        sdx[slot] = yo;                        // silu applied in epilogue
    }

    // ---- epilogue: stream z once per row; wave w covers its own chunks only
    const float* gz0 = z + base0; const float* gz1 = z + base1;
    float* go0 = out + base0;     float* go1 = out + base1;
    for (int k=0;k<512;k+=256){
        const int t0 = w*512 + k + lane*4;
        const float4 zv0 = *(const float4*)(gz0 + t0);
        const float4 zv1 = *(const float4*)(gz1 + t0);
        const float zz0[4]={zv0.x,zv0.y,zv0.z,zv0.w}, zz1[4]={zv1.x,zv1.y,zv1.z,zv1.w};
        float o0[4], o1[4];
#pragma unroll
        for (int j=0;j<4;++j){
            const int t = t0 + j, r = t & 7, c = t >> 3;
            const float2 wd = sdx[r*NCH + (c^r)];
            const float s0 = frcp(1.f + fexp2(-zz0[j]*LOG2E));
            const float s1 = frcp(1.f + fexp2(-zz1[j]*LOG2E));
            o0[j] = wd.x * (zz0[j]*s0);
            o1[j] = wd.y * (zz1[j]*s1);
        }
        float4 a  = {o0[0],o0[1],o0[2],o0[3]};
        float4 bq = {o1[0],o1[1],o1[2],o1[3]};
        *(float4*)(go0 + t0) = a;
        *(float4*)(go1 + t0) = bq;
    }
}

extern "C" void kernel_launch(void* const* d_in, const int* in_sizes, int n_in,
                              void* d_out, int out_size, void* d_ws, size_t ws_size,
                              hipStream_t stream) {
    const float* x     = (const float*)d_in[0];
    const float* delta = (const float*)d_in[1];
    const float* A     = (const float*)d_in[2];
    const float* B     = (const float*)d_in[3];
    const float* C     = (const float*)d_in[4];
    const float* Dv    = (const float*)d_in[5];
    const float* z     = (const float*)d_in[6];
    float* out = (float*)d_out;

    __half* BC = (__half*)d_ws;               // 131072 halfs = 256 KB

    transpose_bc<<<dim3(64), dim3(256), 0, stream>>>(B, C, BC);
    ssm_scan<<<dim3(DM), dim3(256), 0, stream>>>(x, delta, A, Dv, z, BC, out);
}